// Round 3
// baseline (1830.664 us; speedup 1.0000x reference)
//
#include <hip/hip_runtime.h>
#include <math.h>

#define NXg 256
#define NYg 256
#define BIGV 1.0e6f
#define UP 66          // uL pitch: all systolic LDS ops land <=2-way bank aliased (free)
#define FP 66          // fL pitch: stride-65/67 per lane -> 2-way max
#define NROUNDS 8      // halo-exchange rounds: worst tile-Manhattan path 6 + slack
#define MAXSETS 6      // concurrent 4-direction wavefront sets per round (early exit)

// ---------------- init: u = BIG everywhere, seed 4 cells around source ----------------
__global__ void eik_init(const float* __restrict__ f, const float* __restrict__ src,
                         float* __restrict__ u) {
    int t = blockIdx.x * blockDim.x + threadIdx.x;   // 16384 threads, 4 cells each
    float sx = src[0], sy = src[1];
    int ix0 = (int)fminf(fmaxf(floorf(sx), 0.f), (float)(NXg - 2));
    int iy0 = (int)fminf(fmaxf(floorf(sy), 0.f), (float)(NYg - 2));
#pragma unroll
    for (int k = 0; k < 4; ++k) {
        int cid = t + (k << 14);
        int gx = cid >> 8, gy = cid & 255;
        float val = BIGV;
        if ((gx == ix0 || gx == ix0 + 1) && (gy == iy0 || gy == iy0 + 1)) {
            float dx = (float)gx - sx, dy = (float)gy - sy;
            val = sqrtf(dx * dx + dy * dy) * f[cid];   // H == 1
        }
        u[cid] = val;
    }
}

__device__ __forceinline__ float eik_relax(float u0, float a, float b, float fh) {
    float one  = fminf(a, b) + fh;
    float diff = a - b;
    float disc = fmaxf(2.0f * fh * fh - diff * diff, 0.0f);
    float two  = 0.5f * (a + b + sqrtf(disc));
    float cand = (fabsf(diff) >= fh) ? one : two;
    return fminf(u0, cand);
}

// ------- one halo-exchange round: Zhao-style anti-diagonal wavefront GS sweeps --------
// 16 blocks x one 64x64 tile. Lane l owns column x=l. Wave w runs quadrant direction w
// (all 4 concurrently; racy min-updates are monotone-safe). Within a pass, step t
// relaxes the cells on diagonal t; upwind neighbors were written at step t-1 and are
// seen fresh via the in-order per-wave LDS pipeline (volatile stops compiler reorder).
__global__ __launch_bounds__(256) void eik_fsm(const float* __restrict__ f,
                                               float* __restrict__ u) {
    __shared__ float uLs[66 * UP];   // [x+1][y+1], x,y in [-1,64]
    __shared__ float fL[64 * FP];
    __shared__ int   sflag[4];
    __shared__ int   s_seen;
    volatile float* uL = uLs;

    const int t = threadIdx.x;
    const int l = t & 63;            // lane: owns column x = l
    const int w = t >> 6;            // wave: quadrant direction
    const int bx = blockIdx.x & 3, by = blockIdx.x >> 2;
    const int x0 = bx * 64, y0 = by * 64;

    if (t < 4) sflag[t] = 0;
    if (t == 0) s_seen = 0;
    __syncthreads();

    // ---- load u tile + 1-cell halo (BIG outside grid) ----
    int seen = 0;
    for (int idx = t; idx < 66 * 66; idx += 256) {
        int r = idx / 66, c = idx % 66;
        int gx = x0 + r - 1, gy = y0 + c - 1;
        float v = BIGV;
        if (gx >= 0 && gx < NXg && gy >= 0 && gy < NYg) v = u[(gx << 8) + gy];
        uLs[r * UP + c] = v;
        seen |= (v < BIGV) ? 1 : 0;
    }
    // ---- load f tile ----
    for (int idx = t; idx < 64 * 64; idx += 256) {
        int r = idx >> 6, c = idx & 63;
        fL[r * FP + c] = f[((x0 + r) << 8) + (y0 + c)];
    }
    if (seen) s_seen = 1;
    __syncthreads();
    if (!s_seen) return;             // front hasn't reached this tile yet (uniform)

    for (int set = 0; set < MAXSETS; ++set) {
        int changed = 0;
        // one quadrant wavefront pass: 127 diagonal steps, no barriers inside
        for (int tt = 0; tt < 127; ++tt) {
            int j = (w == 0) ? (tt - l)            // (+x,+y)
                  : (w == 1) ? (tt - 63 + l)       // (-x,+y)
                  : (w == 2) ? (63 - tt + l)       // (+x,-y)
                             : (126 - tt - l);     // (-x,-y)
            if (j >= 0 && j <= 63) {
                float u0 = uL[(l + 1) * UP + (j + 1)];
                float xm = uL[ l      * UP + (j + 1)];   // upwind-fresh for +x passes
                float xp = uL[(l + 2) * UP + (j + 1)];   // upwind-fresh for -x passes
                float ym = uL[(l + 1) * UP +  j     ];   // upwind-fresh for +y passes
                float yp = uL[(l + 1) * UP + (j + 2)];   // upwind-fresh for -y passes
                float fh = fL[l * FP + j];
                float un = eik_relax(u0, fminf(xm, xp), fminf(ym, yp), fh);
                if (un < u0) { uL[(l + 1) * UP + (j + 1)] = un; changed = 1; }
            }
        }
        int anyc = __any(changed) ? 1 : 0;
        __syncthreads();                       // B1: all passes done, uL writes visible
        if (l == 0) sflag[w] = anyc;
        __syncthreads();                       // B2: flags written
        int tot = sflag[0] | sflag[1] | sflag[2] | sflag[3];
        __syncthreads();                       // B3: all read flags
        if (t < 4) sflag[t] = 0;               // reset for next set (ordered by next B1)
        if (!tot) break;                       // local fixed point certified (uniform)
    }

    __syncthreads();
    // ---- write back interior (each cell owned by exactly one block) ----
    for (int idx = t; idx < 64 * 64; idx += 256) {
        int r = idx >> 6, c = idx & 63;
        u[((x0 + r) << 8) + (y0 + c)] = uLs[(r + 1) * UP + (c + 1)];
    }
}

// ---------------- bilinear interp at picks + add origin time ----------------
__global__ void eik_interp(const float* __restrict__ u,
                           const float* __restrict__ ex,
                           const float* __restrict__ ey,
                           const float* __restrict__ et,
                           float* __restrict__ out, int n) {
    int i = blockIdx.x * blockDim.x + threadIdx.x;
    int stride = gridDim.x * blockDim.x;
    for (; i < n; i += stride) {
        float x = ex[i], y = ey[i];
        int ix0 = (int)fminf(fmaxf(floorf(x), 0.f), (float)(NXg - 2));
        int iy0 = (int)fminf(fmaxf(floorf(y), 0.f), (float)(NYg - 2));
        float xc = fminf(fmaxf(x, 0.f), (float)(NXg - 1));
        float yc = fminf(fmaxf(y, 0.f), (float)(NYg - 1));
        float fx0 = (float)ix0, fy0 = (float)iy0;
        float wx0 = xc - fx0, wx1 = (fx0 + 1.f) - xc;
        float wy0 = yc - fy0, wy1 = (fy0 + 1.f) - yc;
        int base = (ix0 << 8) + iy0;
        float Q00 = u[base],       Q01 = u[base + 1];
        float Q10 = u[base + 256], Q11 = u[base + 257];
        float tt = Q00 * wx1 * wy1 + Q10 * wx0 * wy1
                 + Q01 * wx1 * wy0 + Q11 * wx0 * wy0;
        out[i] = et[i] + tt;
    }
}

extern "C" void kernel_launch(void* const* d_in, const int* in_sizes, int n_in,
                              void* d_out, int out_size, void* d_ws, size_t ws_size,
                              hipStream_t stream) {
    const float* f   = (const float*)d_in[0];
    const float* src = (const float*)d_in[1];
    const float* ex  = (const float*)d_in[2];
    const float* ey  = (const float*)d_in[3];
    const float* et  = (const float*)d_in[4];
    float* out = (float*)d_out;
    float* u   = (float*)d_ws;               // 256 KB travel-time table
    int n = in_sizes[2];

    eik_init<<<64, 256, 0, stream>>>(f, src, u);
    for (int r = 0; r < NROUNDS; ++r)
        eik_fsm<<<16, 256, 0, stream>>>(f, u);
    eik_interp<<<2048, 256, 0, stream>>>(u, ex, ey, et, out, n);
}

// Round 4
// 985.225 us; speedup vs baseline: 1.8581x; 1.8581x over previous
//
#include <hip/hip_runtime.h>
#include <math.h>

#define NXg 256
#define NYg 256
#define BIGV 1.0e6f
#define UP 66          // uL pitch: diagonal access -> per-lane stride 65/67, conflict-free
#define FP 66          // fL pitch: same property
#define NROUNDS 8      // halo-exchange rounds (validated in R3: converges with margin)
#define MAXSETS 6      // concurrent 4-direction wavefront sets per round (early exit)

// ---------------- init: u = BIG everywhere, seed 4 cells around source ----------------
__global__ void eik_init(const float* __restrict__ f, const float* __restrict__ src,
                         float* __restrict__ u) {
    int t = blockIdx.x * blockDim.x + threadIdx.x;   // 16384 threads, 4 cells each
    float sx = src[0], sy = src[1];
    int ix0 = (int)fminf(fmaxf(floorf(sx), 0.f), (float)(NXg - 2));
    int iy0 = (int)fminf(fmaxf(floorf(sy), 0.f), (float)(NYg - 2));
#pragma unroll
    for (int k = 0; k < 4; ++k) {
        int cid = t + (k << 14);
        int gx = cid >> 8, gy = cid & 255;
        float val = BIGV;
        if ((gx == ix0 || gx == ix0 + 1) && (gy == iy0 || gy == iy0 + 1)) {
            float dx = (float)gx - sx, dy = (float)gy - sy;
            val = sqrtf(dx * dx + dy * dy) * f[cid];   // H == 1
        }
        u[cid] = val;
    }
}

__device__ __forceinline__ float eik_relax(float u0, float a, float b, float fh) {
    float one  = fminf(a, b) + fh;
    float diff = a - b;
    float disc = fmaxf(2.0f * fh * fh - diff * diff, 0.0f);
    float two  = 0.5f * (a + b + sqrtf(disc));
    float cand = (fabsf(diff) >= fh) ? one : two;
    return fminf(u0, cand);
}

// ------- one halo-exchange round: anti-diagonal wavefront GS, register/shfl chain -----
// 16 blocks x one 64x64 tile. Lane l owns column x=l; wave w sweeps quadrant w, all 4
// concurrently (racy min-updates stay >= fixed point; a no-change set certifies FP).
// Within a pass, step s relaxes diagonal cells; the fresh y-upwind value is the lane's
// own register from step s-1, the fresh x-upwind value is the neighbor lane's register
// via shfl (boundary lane reads the frozen halo column from LDS). Stale opposite-side
// values come from plain LDS reads (off the critical chain, compiler-overlapped).
__global__ __launch_bounds__(256) void eik_fsm(const float* __restrict__ f,
                                               float* __restrict__ u) {
    __shared__ float uLs[66 * UP];   // [x+1][y+1], x,y in [-1,64]
    __shared__ float fL[64 * FP];
    __shared__ int   s_seen;
    const int t = threadIdx.x;
    const int l = t & 63;            // lane: owns column x = l
    const int w = t >> 6;            // wave: quadrant
    const int bx = blockIdx.x & 3, by = blockIdx.x >> 2;
    const int x0 = bx * 64, y0 = by * 64;

    if (t == 0) s_seen = 0;
    __syncthreads();

    // ---- load u tile + 1-cell halo (BIG outside grid) ----
    int seen = 0;
    for (int idx = t; idx < 66 * 66; idx += 256) {
        int r = idx / 66, c = idx % 66;
        int gx = x0 + r - 1, gy = y0 + c - 1;
        float v = BIGV;
        if (gx >= 0 && gx < NXg && gy >= 0 && gy < NYg) v = u[(gx << 8) + gy];
        uLs[r * UP + c] = v;
        seen |= (v < BIGV) ? 1 : 0;
    }
    // ---- load f tile ----
    for (int idx = t; idx < 64 * 64; idx += 256) {
        int r = idx >> 6, c = idx & 63;
        fL[r * FP + c] = f[((x0 + r) << 8) + (y0 + c)];
    }
    if (seen) s_seen = 1;
    __syncthreads();
    if (!s_seen) return;             // front hasn't reached this tile yet (uniform)

    // wave-uniform quadrant parameters
    const bool xup   = (w == 0) || (w == 2);         // fresh x-neighbor is lane l-1
    const int  j0    = (w == 0) ? -l : (w == 1) ? l - 63 : (w == 2) ? 63 + l : 126 - l;
    const int  dj    = (w < 2) ? 1 : -1;             // j step per s
    const int  yoOff = (w < 2) ? 2 : 0;              // stale opposite-y column offset
    const int  xoRow = xup ? (l + 2) : l;            // stale opposite-x row
    const int  bRow  = xup ? 0 : 65;                 // halo row for boundary lane
    const int  bLane = xup ? 0 : 63;
    const int  initC = (w < 2) ? 0 : 65;             // y-halo init for register chain
    const int  baseu = (l + 1) * UP;

    for (int set = 0; set < MAXSETS; ++set) {
        int changed = 0;
        float un = uLs[baseu + initC];               // fresh-chain register, y-halo init
        int j = j0;
        for (int s = 0; s < 127; ++s, j += dj) {
            int act = (j >= 0) & (j <= 63);
            int jc  = min(max(j, 0), 63);
            // off-chain stale reads (overlap with shfl+compute)
            float u0 = uLs[baseu + jc + 1];
            float xo = uLs[xoRow * UP + jc + 1];
            float yo = uLs[baseu + jc + yoOff];
            float fh = fL[l * FP + jc];
            // fresh x-upwind from neighbor lane's register (prev step)
            float xf = xup ? __shfl_up(un, 1, 64) : __shfl_down(un, 1, 64);
            if (l == bLane) xf = uLs[bRow * UP + jc + 1];
            float a  = fminf(xf, xo);
            float b  = fminf(un, yo);                // un == fresh y-upwind
            float nu = eik_relax(u0, a, b, fh);
            if (act) {
                if (nu < u0) { uLs[baseu + j + 1] = nu; changed = 1; }
                un = nu;
            }
        }
        if (__syncthreads_count(changed) == 0) break;   // local fixed point certified
    }

    __syncthreads();
    // ---- write back interior (each cell owned by exactly one block) ----
    for (int idx = t; idx < 64 * 64; idx += 256) {
        int r = idx >> 6, c = idx & 63;
        u[((x0 + r) << 8) + (y0 + c)] = uLs[(r + 1) * UP + (c + 1)];
    }
}

// ---------------- bilinear interp at picks + add origin time ----------------
__global__ void eik_interp(const float* __restrict__ u,
                           const float* __restrict__ ex,
                           const float* __restrict__ ey,
                           const float* __restrict__ et,
                           float* __restrict__ out, int n) {
    int i = blockIdx.x * blockDim.x + threadIdx.x;
    int stride = gridDim.x * blockDim.x;
    for (; i < n; i += stride) {
        float x = ex[i], y = ey[i];
        int ix0 = (int)fminf(fmaxf(floorf(x), 0.f), (float)(NXg - 2));
        int iy0 = (int)fminf(fmaxf(floorf(y), 0.f), (float)(NYg - 2));
        float xc = fminf(fmaxf(x, 0.f), (float)(NXg - 1));
        float yc = fminf(fmaxf(y, 0.f), (float)(NYg - 1));
        float fx0 = (float)ix0, fy0 = (float)iy0;
        float wx0 = xc - fx0, wx1 = (fx0 + 1.f) - xc;
        float wy0 = yc - fy0, wy1 = (fy0 + 1.f) - yc;
        int base = (ix0 << 8) + iy0;
        float Q00 = u[base],       Q01 = u[base + 1];
        float Q10 = u[base + 256], Q11 = u[base + 257];
        float tt = Q00 * wx1 * wy1 + Q10 * wx0 * wy1
                 + Q01 * wx1 * wy0 + Q11 * wx0 * wy0;
        out[i] = et[i] + tt;
    }
}

extern "C" void kernel_launch(void* const* d_in, const int* in_sizes, int n_in,
                              void* d_out, int out_size, void* d_ws, size_t ws_size,
                              hipStream_t stream) {
    const float* f   = (const float*)d_in[0];
    const float* src = (const float*)d_in[1];
    const float* ex  = (const float*)d_in[2];
    const float* ey  = (const float*)d_in[3];
    const float* et  = (const float*)d_in[4];
    float* out = (float*)d_out;
    float* u   = (float*)d_ws;               // 256 KB travel-time table
    int n = in_sizes[2];

    eik_init<<<64, 256, 0, stream>>>(f, src, u);
    for (int r = 0; r < NROUNDS; ++r)
        eik_fsm<<<16, 256, 0, stream>>>(f, u);
    eik_interp<<<2048, 256, 0, stream>>>(u, ex, ey, et, out, n);
}